// Round 2
// baseline (287.804 us; speedup 1.0000x reference)
//
#include <hip/hip_runtime.h>

// SSIM loss, fully fused, full-width-strip version.
// Block = 512 threads = one 512-wide x 32-tall output strip of one image.
// Per barrier-iteration: 2 rows staged (each thread: 3 aligned float4 loads ->
// channel mean -> 1 ds_write_b128), then 2 rows of separable 11-tap conv
// (horizontal from LDS, vertical via per-thread register ring) + SSIM.

constexpr int KW   = 11;
constexpr int HALF = 5;
constexpr int IMG_H = 512;
constexpr int IMG_W = 512;
constexpr int NB   = 32;
constexpr int NCH  = 3;
constexpr int TR   = 32;                    // strip height
constexpr int BT   = 512;                   // threads per block
constexpr int LW   = IMG_W + 16;            // 8-col zero halo each side
constexpr int NPAIR = (TR + 2 * HALF) / 2;  // 21 row-pairs per strip

__global__ __launch_bounds__(BT, 4)
void ssim_fused(const float* __restrict__ pred,
                const float* __restrict__ targ,
                const float* __restrict__ win,
                float* __restrict__ out)
{
    __shared__ float lP[2][2][LW];   // [buf][row-of-pair][col]
    __shared__ float lT[2][2][LW];
    __shared__ float red[BT / 64];

    const int tid  = threadIdx.x;
    const int nrow = IMG_H / TR;             // 16
    const int img  = blockIdx.x / nrow;
    const int R0   = (blockIdx.x % nrow) * TR;

    // zero the +-8 col halos of all 4 row-slots (both buffers), once
    if (tid < 64) {
        int b = tid & 1, r = (tid >> 1) & 1, s = (tid >> 2) & 1, k = tid >> 3;
        int idx = s ? (IMG_W + 8 + k) : k;
        lP[b][r][idx] = 0.f; lT[b][r][idx] = 0.f;
    }

    // exact 1-D gaussian from the passed 2-D window (w = g x g)
    float g[KW];
    {
        float g5 = sqrtf(win[HALF * KW + HALF]);
        #pragma unroll
        for (int j = 0; j < KW; ++j) g[j] = win[HALF * KW + j] / g5;
    }

    const size_t ims = (size_t)IMG_H * IMG_W;
    // load role: one float4 chunk of one tensor of one row of the pair
    const int chunk   = tid & 127;           // 128 float4 chunks per row
    const int tensor  = (tid >> 7) & 1;      // 0=pred 1=targ
    const int row_off = tid >> 8;            // 0,1: row within pair
    const float* srcb = (tensor ? targ : pred)
                      + (size_t)img * NCH * ims + (size_t)chunk * 4;
    const float inv3 = 1.0f / 3.0f;

    float4 v0, v1, v2;
    auto issue = [&](int pair) {
        int r = R0 - HALF + 2 * pair + row_off;
        if (r >= 0 && r < IMG_H) {
            const float* p = srcb + (size_t)r * IMG_W;
            v0 = *(const float4*)(p);
            v1 = *(const float4*)(p + ims);
            v2 = *(const float4*)(p + 2 * ims);
        } else {
            v0 = make_float4(0.f, 0.f, 0.f, 0.f);
            v1 = v0; v2 = v0;
        }
    };
    auto commit = [&](int pair) {
        float4 m;
        m.x = (v0.x + v1.x + v2.x) * inv3;
        m.y = (v0.y + v1.y + v2.y) * inv3;
        m.z = (v0.z + v1.z + v2.z) * inv3;
        m.w = (v0.w + v1.w + v2.w) * inv3;
        float* dst = tensor ? &lT[pair & 1][row_off][8 + chunk * 4]
                            : &lP[pair & 1][row_off][8 + chunk * 4];
        *(float4*)dst = m;   // 16B-aligned ds_write_b128
    };

    issue(0);
    commit(0);

    // vertical register ring: last 11 horizontal-conv rows (static indexing)
    float hP[KW], hT[KW], hP2[KW], hT2[KW], hPT[KW];
    #pragma unroll
    for (int j = 0; j < KW; ++j) { hP[j]=hT[j]=hP2[j]=hT2[j]=hPT[j]=0.f; }

    const float C1 = 1e-4f, C2 = 9e-4f;
    const int c = tid;                       // output column
    float acc = 0.f;

    for (int it = 0; it < NPAIR; ++it) {
        if (it + 1 < NPAIR) issue(it + 1);   // global loads in flight over compute
        __syncthreads();                     // pair `it` staged; prev readers done
        const int bf = it & 1;
        #pragma unroll
        for (int rr = 0; rr < 2; ++rr) {
            // horizontal 11-tap (stride-1 LDS, conflict-free)
            float sP=0.f, sT=0.f, sP2=0.f, sT2=0.f, sPT=0.f;
            #pragma unroll
            for (int j = 0; j < KW; ++j) {
                float w = g[j];
                float p = lP[bf][rr][c + 3 + j];
                float t = lT[bf][rr][c + 3 + j];
                sP += w * p;     sT += w * t;
                sP2 += w * p * p; sT2 += w * t * t; sPT += w * p * t;
            }
            #pragma unroll
            for (int k = 0; k < KW - 1; ++k) {
                hP[k]=hP[k+1]; hT[k]=hT[k+1]; hP2[k]=hP2[k+1];
                hT2[k]=hT2[k+1]; hPT[k]=hPT[k+1];
            }
            hP[KW-1]=sP; hT[KW-1]=sT; hP2[KW-1]=sP2; hT2[KW-1]=sT2; hPT[KW-1]=sPT;

            int s = 2 * it + rr;             // row sweep index (block-uniform)
            if (s >= 2 * HALF) {
                float mu1=0.f, mu2=0.f, ep2=0.f, et2=0.f, ept=0.f;
                #pragma unroll
                for (int k = 0; k < KW; ++k) {
                    float w = g[k];
                    mu1 += w * hP[k];  mu2 += w * hT[k];
                    ep2 += w * hP2[k]; et2 += w * hT2[k]; ept += w * hPT[k];
                }
                float m11 = mu1*mu1, m22 = mu2*mu2, m12 = mu1*mu2;
                float s1 = ep2 - m11, s2 = et2 - m22, s12 = ept - m12;
                float num = (2.f * m12 + C1) * (2.f * s12 + C2);
                float den = (m11 + m22 + C1) * (s1 + s2 + C2);
                acc += 1.f - num / den;
            }
        }
        if (it + 1 < NPAIR) commit(it + 1);  // write other buffer (safe: barrier-ordered)
    }

    // block reduction
    #pragma unroll
    for (int off = 32; off >= 1; off >>= 1)
        acc += __shfl_down(acc, off, 64);
    if ((tid & 63) == 0) red[tid >> 6] = acc;
    __syncthreads();
    if (tid == 0) {
        float s = 0.f;
        #pragma unroll
        for (int w = 0; w < BT / 64; ++w) s += red[w];
        atomicAdd(out, s * (1.0f / ((float)NB * IMG_H * IMG_W)));
    }
}

extern "C" void kernel_launch(void* const* d_in, const int* in_sizes, int n_in,
                              void* d_out, int out_size, void* d_ws, size_t ws_size,
                              hipStream_t stream) {
    const float* pred = (const float*)d_in[0];
    const float* targ = (const float*)d_in[1];
    const float* win  = (const float*)d_in[2];
    float* out = (float*)d_out;

    hipMemsetAsync(out, 0, sizeof(float), stream);

    dim3 grid(NB * (IMG_H / TR));   // 32 * 16 = 512 blocks, 8 waves each
    ssim_fused<<<grid, BT, 0, stream>>>(pred, targ, win, out);
}

// Round 3
// 131.736 us; speedup vs baseline: 2.1847x; 2.1847x over previous
//
#include <hip/hip_runtime.h>

// SSIM loss, fully fused (R3): channel-mean + separable 11x11 Gaussian via
// horizontal conv from LDS + vertical conv in a 12-slot per-thread register
// ring (2 rows per barrier, shift-by-2), + SSIM map + global mean reduce.
// 1 col/thread, 256-col x 32-row tiles, grid 1024 for 16 waves/CU.

constexpr int KW   = 11;
constexpr int HALF = 5;
constexpr int IMG_H = 512;
constexpr int IMG_W = 512;
constexpr int NB   = 32;
constexpr int NCH  = 3;
constexpr int TC   = 256;                 // tile cols = block size
constexpr int TR   = 32;                  // tile rows
constexpr int BT   = 256;
constexpr int LW   = TC + 2 * HALF;       // 266
constexpr int NP   = (TR + 2 * HALF) / 2; // 21 row-pairs

__global__ __launch_bounds__(BT)
void ssim_fused(const float* __restrict__ pred,
                const float* __restrict__ targ,
                const float* __restrict__ win,
                float* __restrict__ out)
{
    __shared__ float lP[2][2][LW];   // [buf][row-of-pair][col]
    __shared__ float lT[2][2][LW];
    __shared__ float red[BT / 64];

    const int tid = threadIdx.x;
    int bid = blockIdx.x;
    const int cb  = bid & 1;          // 2 col-tiles
    const int rb  = (bid >> 1) & 15;  // 16 row-strips
    const int img = bid >> 5;         // 32 images
    const int C0 = cb * TC, R0 = rb * TR;

    // 1-D gaussian (symmetric: 6 unique weights) from the passed 2-D window
    float gs[6];
    {
        float g5 = sqrtf(win[HALF * KW + HALF]);
        #pragma unroll
        for (int j = 0; j < 6; ++j) gs[j] = win[HALF * KW + j] / g5;
    }
    auto W = [&](int j) { return gs[j <= 5 ? j : 10 - j]; };  // j static

    const size_t ims = (size_t)IMG_H * IMG_W;
    const float* pb = pred + (size_t)img * NCH * ims;
    const float* tb = targ + (size_t)img * NCH * ims;
    const int col0 = C0 - HALF + tid;        // lds slot tid
    const int col1 = col0 + TC;              // lds slot tid+TC
    const bool has2 = tid < (LW - TC);       // 10 halo threads
    const float inv3 = 1.0f / 3.0f;

    float vv[2][4];   // prefetch: [row-of-pair][P0,T0,P1,T1]

    auto issue = [&](int pair) {
        #pragma unroll
        for (int rr = 0; rr < 2; ++rr) {
            int r = R0 - HALF + 2 * pair + rr;
            float a0 = 0.f, b0 = 0.f, a1 = 0.f, b1 = 0.f;
            if (r >= 0 && r < IMG_H) {
                if (col0 >= 0 && col0 < IMG_W) {
                    size_t ad = (size_t)r * IMG_W + col0;
                    a0 = (pb[ad] + pb[ad + ims] + pb[ad + 2 * ims]) * inv3;
                    b0 = (tb[ad] + tb[ad + ims] + tb[ad + 2 * ims]) * inv3;
                }
                if (has2 && col1 < IMG_W) {
                    size_t ad = (size_t)r * IMG_W + col1;
                    a1 = (pb[ad] + pb[ad + ims] + pb[ad + 2 * ims]) * inv3;
                    b1 = (tb[ad] + tb[ad + ims] + tb[ad + 2 * ims]) * inv3;
                }
            }
            vv[rr][0] = a0; vv[rr][1] = b0; vv[rr][2] = a1; vv[rr][3] = b1;
        }
    };
    auto commit = [&](int pair) {
        const int buf = pair & 1;
        #pragma unroll
        for (int rr = 0; rr < 2; ++rr) {
            lP[buf][rr][tid] = vv[rr][0];
            lT[buf][rr][tid] = vv[rr][1];
            if (has2) {
                lP[buf][rr][tid + TC] = vv[rr][2];
                lT[buf][rr][tid + TC] = vv[rr][3];
            }
        }
    };

    // 12-slot vertical ring (statically indexed everywhere)
    float rP[12], rT[12], rP2[12], rT2[12], rPT[12];
    #pragma unroll
    for (int k = 0; k < 12; ++k) { rP[k]=rT[k]=rP2[k]=rT2[k]=rPT[k]=0.f; }

    const float C1 = 1e-4f, C2 = 9e-4f;
    float acc = 0.f;

    issue(0);
    for (int i = 0; i < NP; ++i) {
        commit(i);
        if (i + 1 < NP) issue(i + 1);   // next-pair loads in flight over compute
        __syncthreads();
        const int buf = i & 1;

        // horizontal 11-tap for the 2 staged rows -> ring slots 10, 11
        #pragma unroll
        for (int rr = 0; rr < 2; ++rr) {
            float sP=0.f, sT=0.f, sP2=0.f, sT2=0.f, sPT=0.f;
            #pragma unroll
            for (int j = 0; j < KW; ++j) {
                float w = W(j);
                float p = lP[buf][rr][tid + j];
                float t = lT[buf][rr][tid + j];
                sP += w * p;      sT += w * t;
                sP2 += w * p * p; sT2 += w * t * t; sPT += w * p * t;
            }
            rP[10+rr]=sP; rT[10+rr]=sT; rP2[10+rr]=sP2; rT2[10+rr]=sT2; rPT[10+rr]=sPT;
        }

        // vertical 11-tap + SSIM for 2 output rows (centers R0+2i-10, +1)
        if (i >= 5) {
            #pragma unroll
            for (int off = 0; off < 2; ++off) {
                float mu1=0.f, mu2=0.f, ep2=0.f, et2=0.f, ept=0.f;
                #pragma unroll
                for (int k = 0; k < KW; ++k) {
                    float w = W(k);
                    mu1 += w * rP[off+k];  mu2 += w * rT[off+k];
                    ep2 += w * rP2[off+k]; et2 += w * rT2[off+k]; ept += w * rPT[off+k];
                }
                float m11 = mu1*mu1, m22 = mu2*mu2, m12 = mu1*mu2;
                float s1 = ep2 - m11, s2 = et2 - m22, s12 = ept - m12;
                float num = (2.f * m12 + C1) * (2.f * s12 + C2);
                float den = (m11 + m22 + C1) * (s1 + s2 + C2);
                acc += 1.f - num * __builtin_amdgcn_rcpf(den);
            }
        }

        // shift ring by 2 (25 movs/row vs 50 in R1)
        #pragma unroll
        for (int k = 0; k < 10; ++k) {
            rP[k]=rP[k+2]; rT[k]=rT[k+2]; rP2[k]=rP2[k+2];
            rT2[k]=rT2[k+2]; rPT[k]=rPT[k+2];
        }
    }

    // block reduction
    #pragma unroll
    for (int off = 32; off >= 1; off >>= 1)
        acc += __shfl_down(acc, off, 64);
    if ((tid & 63) == 0) red[tid >> 6] = acc;
    __syncthreads();
    if (tid == 0) {
        float s = 0.f;
        #pragma unroll
        for (int w = 0; w < BT / 64; ++w) s += red[w];
        atomicAdd(out, s * (1.0f / ((float)NB * IMG_H * IMG_W)));
    }
}

extern "C" void kernel_launch(void* const* d_in, const int* in_sizes, int n_in,
                              void* d_out, int out_size, void* d_ws, size_t ws_size,
                              hipStream_t stream) {
    const float* pred = (const float*)d_in[0];
    const float* targ = (const float*)d_in[1];
    const float* win  = (const float*)d_in[2];
    float* out = (float*)d_out;

    hipMemsetAsync(out, 0, sizeof(float), stream);

    dim3 grid(NB * 16 * 2);   // 1024 blocks -> 4 blocks/CU, 16 waves/CU
    ssim_fused<<<grid, BT, 0, stream>>>(pred, targ, win, out);
}

// Round 4
// 87.099 us; speedup vs baseline: 3.3043x; 1.5125x over previous
//
#include <hip/hip_runtime.h>

// SSIM loss, fully fused (R4): R3's register-ring compute core in a
// 512-thread full-width-strip block (the only shape that reached 45% occ).
// Per row-pair: each thread does 3 aligned float4 loads (one tensor, one row,
// 3 channels) -> channel mean -> 1 ds_write_b128; then every thread runs the
// separable conv for its column: horizontal 11-tap from LDS, vertical 11-tap
// via a 12-slot per-thread register ring (shift-by-2), SSIM, block reduce.

constexpr int KW   = 11;
constexpr int HALF = 5;
constexpr int IMG_H = 512;
constexpr int IMG_W = 512;
constexpr int NB   = 32;
constexpr int NCH  = 3;
constexpr int TR   = 32;                  // strip height
constexpr int BT   = 512;                 // threads = cols
constexpr int LW   = IMG_W + 16;          // 528: 8-slot halo each side
constexpr int NP   = (TR + 2 * HALF) / 2; // 21 row-pairs

__global__ __launch_bounds__(BT)
void ssim_fused(const float* __restrict__ pred,
                const float* __restrict__ targ,
                const float* __restrict__ win,
                float* __restrict__ out)
{
    __shared__ float lP[2][2][LW];   // [buf][row-of-pair][col+8]
    __shared__ float lT[2][2][LW];
    __shared__ float red[BT / 64];

    const int tid  = threadIdx.x;
    const int nrow = IMG_H / TR;             // 16
    const int img  = blockIdx.x / nrow;
    const int R0   = (blockIdx.x % nrow) * TR;

    // zero the 8-slot halos of all 4 row-slots (both buffers), once
    if (tid < 128) {
        int b = tid & 1, r = (tid >> 1) & 1, s = (tid >> 2) & 1, k = tid >> 3;
        int idx = s ? (IMG_W + 8 + k) : k;
        lP[b][r][idx] = 0.f; lT[b][r][idx] = 0.f;
    }

    // exact 1-D gaussian (symmetric, 6 unique) from the passed 2-D window
    float gs[6];
    {
        float g5 = sqrtf(win[HALF * KW + HALF]);
        #pragma unroll
        for (int j = 0; j < 6; ++j) gs[j] = win[HALF * KW + j] / g5;
    }
    auto W = [&](int j) { return gs[j <= 5 ? j : 10 - j]; };  // j static

    const size_t ims = (size_t)IMG_H * IMG_W;
    // load role: one float4 chunk of one tensor of one row of the pair
    const int chunk   = tid & 127;           // 128 float4 chunks per row
    const int tensor  = (tid >> 7) & 1;      // 0=pred 1=targ
    const int row_off = tid >> 8;            // row within pair
    const float* srcb = (tensor ? targ : pred)
                      + (size_t)img * NCH * ims + (size_t)chunk * 4;
    const float inv3 = 1.0f / 3.0f;

    float4 v0, v1, v2;
    auto issue = [&](int pair) {
        int r = R0 - HALF + 2 * pair + row_off;
        if (r >= 0 && r < IMG_H) {
            const float* p = srcb + (size_t)r * IMG_W;
            v0 = *(const float4*)(p);
            v1 = *(const float4*)(p + ims);
            v2 = *(const float4*)(p + 2 * ims);
        } else {
            v0 = make_float4(0.f, 0.f, 0.f, 0.f);
            v1 = v0; v2 = v0;
        }
    };
    auto commit = [&](int pair) {
        float4 m;
        m.x = (v0.x + v1.x + v2.x) * inv3;
        m.y = (v0.y + v1.y + v2.y) * inv3;
        m.z = (v0.z + v1.z + v2.z) * inv3;
        m.w = (v0.w + v1.w + v2.w) * inv3;
        float* dst = tensor ? &lT[pair & 1][row_off][8 + chunk * 4]
                            : &lP[pair & 1][row_off][8 + chunk * 4];
        *(float4*)dst = m;   // 16B-aligned ds_write_b128
    };

    // 12-slot vertical ring (statically indexed everywhere)
    float rP[12], rT[12], rP2[12], rT2[12], rPT[12];
    #pragma unroll
    for (int k = 0; k < 12; ++k) { rP[k]=rT[k]=rP2[k]=rT2[k]=rPT[k]=0.f; }

    const float C1 = 1e-4f, C2 = 9e-4f;
    const int c = tid;                       // output column
    float acc = 0.f;

    issue(0);
    for (int i = 0; i < NP; ++i) {
        commit(i);
        if (i + 1 < NP) issue(i + 1);   // next-pair loads in flight over compute
        __syncthreads();
        const int buf = i & 1;

        // horizontal 11-tap for the 2 staged rows -> ring slots 10, 11
        #pragma unroll
        for (int rr = 0; rr < 2; ++rr) {
            float sP=0.f, sT=0.f, sP2=0.f, sT2=0.f, sPT=0.f;
            #pragma unroll
            for (int j = 0; j < KW; ++j) {
                float w = W(j);
                float p = lP[buf][rr][c + 3 + j];   // col c-5+j
                float t = lT[buf][rr][c + 3 + j];
                sP += w * p;      sT += w * t;
                sP2 += w * p * p; sT2 += w * t * t; sPT += w * p * t;
            }
            rP[10+rr]=sP; rT[10+rr]=sT; rP2[10+rr]=sP2; rT2[10+rr]=sT2; rPT[10+rr]=sPT;
        }

        // vertical 11-tap + SSIM for 2 output rows
        if (i >= 5) {
            #pragma unroll
            for (int off = 0; off < 2; ++off) {
                float mu1=0.f, mu2=0.f, ep2=0.f, et2=0.f, ept=0.f;
                #pragma unroll
                for (int k = 0; k < KW; ++k) {
                    float w = W(k);
                    mu1 += w * rP[off+k];  mu2 += w * rT[off+k];
                    ep2 += w * rP2[off+k]; et2 += w * rT2[off+k]; ept += w * rPT[off+k];
                }
                float m11 = mu1*mu1, m22 = mu2*mu2, m12 = mu1*mu2;
                float s1 = ep2 - m11, s2 = et2 - m22, s12 = ept - m12;
                float num = (2.f * m12 + C1) * (2.f * s12 + C2);
                float den = (m11 + m22 + C1) * (s1 + s2 + C2);
                acc += 1.f - num * __builtin_amdgcn_rcpf(den);
            }
        }

        // shift ring by 2
        #pragma unroll
        for (int k = 0; k < 10; ++k) {
            rP[k]=rP[k+2]; rT[k]=rT[k+2]; rP2[k]=rP2[k+2];
            rT2[k]=rT2[k+2]; rPT[k]=rPT[k+2];
        }
    }

    // block reduction
    #pragma unroll
    for (int off = 32; off >= 1; off >>= 1)
        acc += __shfl_down(acc, off, 64);
    if ((tid & 63) == 0) red[tid >> 6] = acc;
    __syncthreads();
    if (tid == 0) {
        float s = 0.f;
        #pragma unroll
        for (int w = 0; w < BT / 64; ++w) s += red[w];
        atomicAdd(out, s * (1.0f / ((float)NB * IMG_H * IMG_W)));
    }
}

extern "C" void kernel_launch(void* const* d_in, const int* in_sizes, int n_in,
                              void* d_out, int out_size, void* d_ws, size_t ws_size,
                              hipStream_t stream) {
    const float* pred = (const float*)d_in[0];
    const float* targ = (const float*)d_in[1];
    const float* win  = (const float*)d_in[2];
    float* out = (float*)d_out;

    hipMemsetAsync(out, 0, sizeof(float), stream);

    dim3 grid(NB * (IMG_H / TR));   // 512 blocks, 8 waves each
    ssim_fused<<<grid, BT, 0, stream>>>(pred, targ, win, out);
}